// Round 11
// baseline (732.777 us; speedup 1.0000x reference)
//
#include <hip/hip_runtime.h>
#include <hip/hip_bf16.h>
#include <hip/hip_fp16.h>
#include <math.h>

// DAGNN propagation, CSR-gather, fp16 state.
// Round 11: FEATURE-PLANE PARTITIONED hops. State stored as 8 planes per hop
// (plane c = [N][8] fp16 = 1.6 MB, fits one XCD L2). Block b%8 = plane/XCD
// partition -> all random gathers hit the block's OWN L2-resident plane
// instead of the ~4 TB/s LLC random plateau. Hop is gate-free (readout is a
// separate final kernel), so feature separation is exact.

#define DIM 64
#define NPART 8          // 8 XCDs; blockIdx%8 ~ XCD round-robin heuristic

// ---- zero int region ----
__global__ void zero_int_kernel(int* __restrict__ p, int n) {
    int i = blockIdx.x * blockDim.x + threadIdx.x;
    if (i < n) p[i] = 0;
}

// ---- partitioned in-degree ----
__global__ void degree_part_kernel(const int* __restrict__ dst, int* __restrict__ deg,
                                   int E, int loN_per, int N) {
    int p   = blockIdx.x & (NPART - 1);
    int sub = blockIdx.x >> 3;
    int nsub = gridDim.x >> 3;
    int lo = p * loN_per;
    int hi = lo + loN_per; if (hi > N) hi = N;
    for (int e = sub * blockDim.x + threadIdx.x; e < E; e += nsub * blockDim.x) {
        int d = dst[e];
        if (d >= lo && d < hi) atomicAdd(&deg[d], 1);
    }
}

// ---- norm = deg^-0.5 ----
__global__ void norm_kernel(const int* __restrict__ deg, float* __restrict__ norm, int N) {
    int i = blockIdx.x * blockDim.x + threadIdx.x;
    if (i < N) norm[i] = rsqrtf((float)deg[i]);
}

// ---- exclusive scan, stage 1 ----
__global__ void scan1_kernel(const int* __restrict__ deg, int* __restrict__ rp,
                             int* __restrict__ chunk_sums, int N) {
    __shared__ int lds[256];
    int t = threadIdx.x;
    int base = blockIdx.x * 1024 + t * 4;
    int v0 = (base + 0 < N) ? deg[base + 0] : 0;
    int v1 = (base + 1 < N) ? deg[base + 1] : 0;
    int v2 = (base + 2 < N) ? deg[base + 2] : 0;
    int v3 = (base + 3 < N) ? deg[base + 3] : 0;
    int tsum = v0 + v1 + v2 + v3;
    lds[t] = tsum;
    __syncthreads();
    for (int off = 1; off < 256; off <<= 1) {
        int x = (t >= off) ? lds[t - off] : 0;
        __syncthreads();
        lds[t] += x;
        __syncthreads();
    }
    int excl = lds[t] - tsum;
    if (t == 255) chunk_sums[blockIdx.x] = lds[255];
    int p = excl;
    if (base + 0 < N) rp[base + 0] = p; p += v0;
    if (base + 1 < N) rp[base + 1] = p; p += v1;
    if (base + 2 < N) rp[base + 2] = p; p += v2;
    if (base + 3 < N) rp[base + 3] = p;
}

// ---- exclusive scan, stage 2 (single block) ----
__global__ void scan2_kernel(int* __restrict__ chunk_sums, int B) {
    __shared__ int lds[256];
    int t = threadIdx.x;
    int v = (t < B) ? chunk_sums[t] : 0;
    lds[t] = v;
    __syncthreads();
    for (int off = 1; off < 256; off <<= 1) {
        int x = (t >= off) ? lds[t - off] : 0;
        __syncthreads();
        lds[t] += x;
        __syncthreads();
    }
    if (t < B) chunk_sums[t] = lds[t] - v;
}

// ---- scan stage 3 ----
__global__ void scan3_kernel(int* __restrict__ rp, const int* __restrict__ chunk_sums,
                             int* __restrict__ cursor, int N, int E) {
    int i = blockIdx.x * blockDim.x + threadIdx.x;
    if (i < N) {
        int val = rp[i] + chunk_sums[i >> 10];
        rp[i] = val;
        cursor[i] = val;
    }
    if (i == 0) rp[N] = E;
}

// ---- partitioned CSR fill ----
__global__ void fill_part_kernel(const int* __restrict__ src, const int* __restrict__ dst,
                                 int* __restrict__ cursor, int* __restrict__ col,
                                 int E, int loN_per, int N) {
    int p   = blockIdx.x & (NPART - 1);
    int sub = blockIdx.x >> 3;
    int nsub = gridDim.x >> 3;
    int lo = p * loN_per;
    int hi = lo + loN_per; if (hi > N) hi = N;
    for (int e = sub * blockDim.x + threadIdx.x; e < E; e += nsub * blockDim.x) {
        int d = dst[e];
        if (d >= lo && d < hi) {
            int pos = atomicAdd(&cursor[d], 1);
            col[pos] = src[e];
        }
    }
}

// ---- init: w0 planes; plane c holds feats[:, 8c..8c+8)*norm ----
// layout: plane(k,c) base = wbase + ((k*8 + c)*N)*8 halfs; node n at +n*8
__global__ void init_w0_plane_kernel(const float* __restrict__ feats,
                                     const float* __restrict__ norm,
                                     __half* __restrict__ w, int N) {
    int wv   = threadIdx.x >> 6;
    int lane = threadIdx.x & 63;
    int n = blockIdx.x * 32 + wv * 8 + (lane >> 3);
    int c = lane & 7;
    if (n >= N) return;
    float nm = norm[n];
    const float4* f = (const float4*)(feats + (size_t)n * DIM + c * 8);
    float4 a = f[0], b = f[1];
    __half2 hv[4];
    hv[0] = __floats2half2_rn(a.x * nm, a.y * nm);
    hv[1] = __floats2half2_rn(a.z * nm, a.w * nm);
    hv[2] = __floats2half2_rn(b.x * nm, b.y * nm);
    hv[3] = __floats2half2_rn(b.z * nm, b.w * nm);
    *(float4*)(w + ((size_t)c * N + n) * 8) = *(const float4*)hv;
}

// ---- plane hop: block handles chunk p = blockIdx%8 only; gathers stay in
// the block's (XCD-local) 1.6 MB plane. wave = 8 nodes x 8 edge slots. ----
__global__ void gather_hop_plane_kernel(const __half* __restrict__ wk,   // hop-k base (8 planes)
                                        const int* __restrict__ rp,
                                        const int* __restrict__ col,
                                        const float* __restrict__ norm,
                                        __half* __restrict__ wnext,      // hop-k+1 base
                                        int N) {
    int p  = blockIdx.x & (NPART - 1);   // feature chunk == XCD partition
    int g  = blockIdx.x >> 3;
    int wv   = threadIdx.x >> 6;
    int lane = threadIdx.x & 63;
    int nsub = lane >> 3;    // node sub 0..7  (lane bits 3..5)
    int e    = lane & 7;     // edge slot 0..7 (lane bits 0..2)
    int n = g * 32 + wv * 8 + nsub;
    if (n >= N) return;      // whole octet exits together; folds are octet-local

    const __half* plane = wk + (size_t)p * N * 8;

    int beg = rp[n];
    int end = rp[n + 1];
    float nm = norm[n];

    float acc[8];
    #pragma unroll
    for (int i = 0; i < 8; ++i) acc[i] = 0.0f;

    // fast path: trips 0,1 with unconditional loads (clamped addr), masked acc.
    // covers deg <= 16 (~84% of nodes) with both gathers in flight together.
    {
        int last = end - 1;               // deg >= 1 (self-loop)
        int j0 = beg + e;
        int j1 = j0 + 8;
        int a0 = j0 <= last ? j0 : last;
        int a1 = j1 <= last ? j1 : last;
        int cc0 = col[a0];
        int cc1 = col[a1];
        float4 raw0 = *(const float4*)(plane + (size_t)cc0 * 8);
        float4 raw1 = *(const float4*)(plane + (size_t)cc1 * 8);
        if (j0 < end) {
            const __half2* h2 = (const __half2*)&raw0;
            float2 f0 = __half22float2(h2[0]);
            float2 f1 = __half22float2(h2[1]);
            float2 f2 = __half22float2(h2[2]);
            float2 f3 = __half22float2(h2[3]);
            acc[0] += f0.x; acc[1] += f0.y;
            acc[2] += f1.x; acc[3] += f1.y;
            acc[4] += f2.x; acc[5] += f2.y;
            acc[6] += f3.x; acc[7] += f3.y;
        }
        if (j1 < end) {
            const __half2* h2 = (const __half2*)&raw1;
            float2 f0 = __half22float2(h2[0]);
            float2 f1 = __half22float2(h2[1]);
            float2 f2 = __half22float2(h2[2]);
            float2 f3 = __half22float2(h2[3]);
            acc[0] += f0.x; acc[1] += f0.y;
            acc[2] += f1.x; acc[3] += f1.y;
            acc[4] += f2.x; acc[5] += f2.y;
            acc[6] += f3.x; acc[7] += f3.y;
        }
    }
    // tail (deg > 16): per-lane divergent loop, no shuffles inside -> safe
    for (int j = beg + e + 16; j < end; j += 8) {
        int cc = col[j];
        float4 raw = *(const float4*)(plane + (size_t)cc * 8);
        const __half2* h2 = (const __half2*)&raw;
        float2 f0 = __half22float2(h2[0]);
        float2 f1 = __half22float2(h2[1]);
        float2 f2 = __half22float2(h2[2]);
        float2 f3 = __half22float2(h2[3]);
        acc[0] += f0.x; acc[1] += f0.y;
        acc[2] += f1.x; acc[3] += f1.y;
        acc[4] += f2.x; acc[5] += f2.y;
        acc[6] += f3.x; acc[7] += f3.y;
    }

    // fold edge slots within the octet (xor 1,2,4 stays in bits 0..2)
    #pragma unroll
    for (int off = 1; off < 8; off <<= 1) {
        #pragma unroll
        for (int i = 0; i < 8; ++i) acc[i] += __shfl_xor(acc[i], off, 64);
    }

    if (e == 0) {
        float n2 = nm * nm;
        __half2 hv[4];
        hv[0] = __floats2half2_rn(acc[0] * n2, acc[1] * n2);
        hv[1] = __floats2half2_rn(acc[2] * n2, acc[3] * n2);
        hv[2] = __floats2half2_rn(acc[4] * n2, acc[5] * n2);
        hv[3] = __floats2half2_rn(acc[6] * n2, acc[7] * n2);
        *(float4*)(wnext + ((size_t)p * N + n) * 8) = *(const float4*)hv;
    }
}

// ---- wide readout over plane layout: lanes = (k-slot x chunk) ----
// h_k[n, 8c..8c+8) = wbase[(k*8+c)*N + n] * inm
__global__ void readout_plane_kernel(const __half* __restrict__ wbase,
                                     const float* __restrict__ norm,
                                     const float* __restrict__ s,
                                     float* __restrict__ out,
                                     int N, int nk) {
    int n = blockIdx.x * (blockDim.x >> 6) + (threadIdx.x >> 6);
    if (n >= N) return;
    int lane  = threadIdx.x & 63;
    int e_sub = lane >> 3;   // k slot 0..7
    int c     = lane & 7;    // feature chunk

    float4 sa = *(const float4*)(s + (c << 3));
    float4 sb = *(const float4*)(s + (c << 3) + 4);

    float inm = 1.0f / norm[n];
    float acc[8];
    #pragma unroll
    for (int i = 0; i < 8; ++i) acc[i] = 0.0f;

    #pragma unroll
    for (int iter = 0; iter < 2; ++iter) {
        int k = e_sub + iter * 8;
        float h[8];
        if (k < nk) {
            float4 raw = *(const float4*)(wbase + ((size_t)(k * 8 + c) * N + n) * 8);
            const __half2* h2 = (const __half2*)&raw;
            float2 f0 = __half22float2(h2[0]);
            float2 f1 = __half22float2(h2[1]);
            float2 f2 = __half22float2(h2[2]);
            float2 f3 = __half22float2(h2[3]);
            h[0] = f0.x * inm; h[1] = f0.y * inm;
            h[2] = f1.x * inm; h[3] = f1.y * inm;
            h[4] = f2.x * inm; h[5] = f2.y * inm;
            h[6] = f3.x * inm; h[7] = f3.y * inm;
        } else {
            #pragma unroll
            for (int i = 0; i < 8; ++i) h[i] = 0.0f;
        }
        float p = h[0] * sa.x + h[1] * sa.y + h[2] * sa.z + h[3] * sa.w
                + h[4] * sb.x + h[5] * sb.y + h[6] * sb.z + h[7] * sb.w;
        #pragma unroll
        for (int off = 1; off < 8; off <<= 1) p += __shfl_xor(p, off, 64);
        float gate = 1.0f / (1.0f + expf(-p));
        #pragma unroll
        for (int i = 0; i < 8; ++i) acc[i] += gate * h[i];
    }

    // fold k slots (lane bits 3..5)
    #pragma unroll
    for (int off = 8; off < 64; off <<= 1) {
        #pragma unroll
        for (int i = 0; i < 8; ++i) acc[i] += __shfl_xor(acc[i], off, 64);
    }

    if (e_sub == 0) {
        size_t rowbase = ((size_t)n << 6) + (c << 3);
        float4 o0 = make_float4(acc[0], acc[1], acc[2], acc[3]);
        float4 o1 = make_float4(acc[4], acc[5], acc[6], acc[7]);
        float4* o = (float4*)(out + rowbase);
        o[0] = o0; o[1] = o1;
    }
}

// ---- fallback (small ws): node-major fused path ----
__global__ void init_kernel(const float* __restrict__ feats,
                            const float* __restrict__ norm,
                            const float* __restrict__ s,
                            float* __restrict__ out,
                            __half* __restrict__ w, int N) {
    int n = blockIdx.x * (blockDim.x >> 6) + (threadIdx.x >> 6);
    int lane = threadIdx.x & 63;
    if (n >= N) return;
    size_t idx = ((size_t)n << 6) + lane;
    float v = feats[idx];
    float p = v * s[lane];
    #pragma unroll
    for (int off = 32; off; off >>= 1) p += __shfl_xor(p, off, 64);
    float gate = 1.0f / (1.0f + expf(-p));
    out[idx] = gate * v;
    w[idx] = __float2half(v * norm[n]);
}

__global__ void gather_hop_kernel(const __half* __restrict__ w,
                                  const int* __restrict__ rp,
                                  const int* __restrict__ col,
                                  const float* __restrict__ norm,
                                  const float* __restrict__ s,
                                  float* __restrict__ out,
                                  __half* __restrict__ wnext,
                                  int N, int write_next) {
    int n = blockIdx.x * (blockDim.x >> 6) + (threadIdx.x >> 6);
    if (n >= N) return;
    int lane = threadIdx.x & 63;
    int e_sub = lane >> 3;
    int c     = lane & 7;

    int beg = rp[n];
    int end = rp[n + 1];

    float acc[8];
    #pragma unroll
    for (int i = 0; i < 8; ++i) acc[i] = 0.0f;

    for (int j = beg + e_sub; j < end; j += 8) {
        int cc = col[j];
        float4 raw = *(const float4*)(w + ((size_t)cc << 6) + (c << 3));
        const __half2* h2 = (const __half2*)&raw;
        float2 f0 = __half22float2(h2[0]);
        float2 f1 = __half22float2(h2[1]);
        float2 f2 = __half22float2(h2[2]);
        float2 f3 = __half22float2(h2[3]);
        acc[0] += f0.x; acc[1] += f0.y;
        acc[2] += f1.x; acc[3] += f1.y;
        acc[4] += f2.x; acc[5] += f2.y;
        acc[6] += f3.x; acc[7] += f3.y;
    }

    #pragma unroll
    for (int off = 8; off < 64; off <<= 1) {
        #pragma unroll
        for (int i = 0; i < 8; ++i) acc[i] += __shfl_xor(acc[i], off, 64);
    }

    float nm = norm[n];
    float v[8];
    #pragma unroll
    for (int i = 0; i < 8; ++i) v[i] = acc[i] * nm;

    float4 sa = *(const float4*)(s + (c << 3));
    float4 sb = *(const float4*)(s + (c << 3) + 4);
    float p = v[0] * sa.x + v[1] * sa.y + v[2] * sa.z + v[3] * sa.w
            + v[4] * sb.x + v[5] * sb.y + v[6] * sb.z + v[7] * sb.w;
    #pragma unroll
    for (int off = 1; off < 8; off <<= 1) p += __shfl_xor(p, off, 64);
    float gate = 1.0f / (1.0f + expf(-p));

    size_t base = ((size_t)n << 6) + (c << 3);
    if (e_sub == 0) {
        float4* o = (float4*)(out + base);
        float4 o0 = o[0], o1 = o[1];
        o0.x += gate * v[0]; o0.y += gate * v[1];
        o0.z += gate * v[2]; o0.w += gate * v[3];
        o1.x += gate * v[4]; o1.y += gate * v[5];
        o1.z += gate * v[6]; o1.w += gate * v[7];
        o[0] = o0; o[1] = o1;
    } else if (e_sub == 1 && write_next) {
        __half2 hv[4];
        hv[0] = __floats2half2_rn(v[0] * nm, v[1] * nm);
        hv[1] = __floats2half2_rn(v[2] * nm, v[3] * nm);
        hv[2] = __floats2half2_rn(v[4] * nm, v[5] * nm);
        hv[3] = __floats2half2_rn(v[6] * nm, v[7] * nm);
        *(float4*)(wnext + base) = *(const float4*)hv;
    }
}

extern "C" void kernel_launch(void* const* d_in, const int* in_sizes, int n_in,
                              void* d_out, int out_size, void* d_ws, size_t ws_size,
                              hipStream_t stream) {
    const float* feats = (const float*)d_in[0];
    const float* s     = (const float*)d_in[1];
    const int*   src   = (const int*)d_in[2];
    const int*   dst   = (const int*)d_in[3];
    float* out = (float*)d_out;

    const int N = in_sizes[0] / DIM;
    const int E = in_sizes[2];
    const int K = 10;

    const int BLK = 256;
    const int wavesPerBlk = BLK / 64;
    const int chunks = (N + 1023) / 1024;   // must be <= 256
    int nodeBlocks = (N + wavesPerBlk - 1) / wavesPerBlk;
    int planeNodeBlocks = (N + 31) / 32;    // 32 nodes/block (4 waves x 8 nodes)
    int intCount = (N + 1) + N + N + E + 256;
    int nodesPerPart = (N + NPART - 1) / NPART;
    const int PART_BLOCKS = 2048;

    size_t stateElems = (size_t)N * DIM;
    size_t need_full = (size_t)N * 4 + (size_t)(K + 1) * stateElems * 2
                     + (size_t)intCount * 4 + 64;
    int full = (ws_size >= need_full) ? 1 : 0;
    int nbuf = full ? (K + 1) : 2;

    float*  norm  = (float*)d_ws;
    __half* wbase = (__half*)(norm + N);
    int*    rp     = (int*)(wbase + (size_t)nbuf * stateElems);
    int*    deg    = rp + (N + 1);
    int*    cursor = deg + N;
    int*    col    = cursor + N;
    int*    chunk  = col + E;

    zero_int_kernel<<<(N + BLK - 1) / BLK, BLK, 0, stream>>>(deg, N);
    degree_part_kernel<<<PART_BLOCKS, BLK, 0, stream>>>(dst, deg, E, nodesPerPart, N);
    norm_kernel<<<(N + BLK - 1) / BLK, BLK, 0, stream>>>(deg, norm, N);

    scan1_kernel<<<chunks, 256, 0, stream>>>(deg, rp, chunk, N);
    scan2_kernel<<<1, 256, 0, stream>>>(chunk, chunks);
    scan3_kernel<<<(N + BLK - 1) / BLK, BLK, 0, stream>>>(rp, chunk, cursor, N, E);
    fill_part_kernel<<<PART_BLOCKS, BLK, 0, stream>>>(src, dst, cursor, col,
                                                      E, nodesPerPart, N);

    if (full) {
        init_w0_plane_kernel<<<planeNodeBlocks, BLK, 0, stream>>>(feats, norm, wbase, N);
        for (int k = 0; k < K; ++k) {
            const __half* cur = wbase + (size_t)k * stateElems;
            __half* nxt = wbase + (size_t)(k + 1) * stateElems;
            gather_hop_plane_kernel<<<NPART * planeNodeBlocks, BLK, 0, stream>>>(
                cur, rp, col, norm, nxt, N);
        }
        readout_plane_kernel<<<nodeBlocks, BLK, 0, stream>>>(wbase, norm, s, out,
                                                             N, K + 1);
    } else {
        __half* wA = wbase;
        __half* wB = wbase + stateElems;
        init_kernel<<<nodeBlocks, BLK, 0, stream>>>(feats, norm, s, out, wA, N);
        __half* cur = wA;
        __half* nxt = wB;
        for (int k = 0; k < K; ++k) {
            int write_next = (k < K - 1) ? 1 : 0;
            gather_hop_kernel<<<nodeBlocks, BLK, 0, stream>>>(cur, rp, col, norm, s,
                                                              out, nxt, N, write_next);
            __half* t = cur; cur = nxt; nxt = t;
        }
    }
}

// Round 12
// 684.472 us; speedup vs baseline: 1.0706x; 1.0706x over previous
//
#include <hip/hip_runtime.h>
#include <hip/hip_bf16.h>
#include <hip/hip_fp16.h>
#include <math.h>

// DAGNN propagation, CSR-gather, fp16 state.
// Round 12: node-major 64B HALF-ROWS. Each hop = 2 sequential launches
// (feature halves); per-launch random working set 6.4 MB (~2x better per-XCD
// L2 residency than 12.8 MB), rows = exactly one 64B line, 4 contiguous
// lanes per row (full line use). Per-instruction line economics identical to
// the round-10 kernel; only the working set shrinks.

#define DIM 64
#define NPART 8

// ---- zero int region ----
__global__ void zero_int_kernel(int* __restrict__ p, int n) {
    int i = blockIdx.x * blockDim.x + threadIdx.x;
    if (i < n) p[i] = 0;
}

// ---- partitioned in-degree ----
__global__ void degree_part_kernel(const int* __restrict__ dst, int* __restrict__ deg,
                                   int E, int loN_per, int N) {
    int p   = blockIdx.x & (NPART - 1);
    int sub = blockIdx.x >> 3;
    int nsub = gridDim.x >> 3;
    int lo = p * loN_per;
    int hi = lo + loN_per; if (hi > N) hi = N;
    for (int e = sub * blockDim.x + threadIdx.x; e < E; e += nsub * blockDim.x) {
        int d = dst[e];
        if (d >= lo && d < hi) atomicAdd(&deg[d], 1);
    }
}

// ---- norm = deg^-0.5 ----
__global__ void norm_kernel(const int* __restrict__ deg, float* __restrict__ norm, int N) {
    int i = blockIdx.x * blockDim.x + threadIdx.x;
    if (i < N) norm[i] = rsqrtf((float)deg[i]);
}

// ---- exclusive scan, stage 1 ----
__global__ void scan1_kernel(const int* __restrict__ deg, int* __restrict__ rp,
                             int* __restrict__ chunk_sums, int N) {
    __shared__ int lds[256];
    int t = threadIdx.x;
    int base = blockIdx.x * 1024 + t * 4;
    int v0 = (base + 0 < N) ? deg[base + 0] : 0;
    int v1 = (base + 1 < N) ? deg[base + 1] : 0;
    int v2 = (base + 2 < N) ? deg[base + 2] : 0;
    int v3 = (base + 3 < N) ? deg[base + 3] : 0;
    int tsum = v0 + v1 + v2 + v3;
    lds[t] = tsum;
    __syncthreads();
    for (int off = 1; off < 256; off <<= 1) {
        int x = (t >= off) ? lds[t - off] : 0;
        __syncthreads();
        lds[t] += x;
        __syncthreads();
    }
    int excl = lds[t] - tsum;
    if (t == 255) chunk_sums[blockIdx.x] = lds[255];
    int p = excl;
    if (base + 0 < N) rp[base + 0] = p; p += v0;
    if (base + 1 < N) rp[base + 1] = p; p += v1;
    if (base + 2 < N) rp[base + 2] = p; p += v2;
    if (base + 3 < N) rp[base + 3] = p;
}

// ---- exclusive scan, stage 2 (single block) ----
__global__ void scan2_kernel(int* __restrict__ chunk_sums, int B) {
    __shared__ int lds[256];
    int t = threadIdx.x;
    int v = (t < B) ? chunk_sums[t] : 0;
    lds[t] = v;
    __syncthreads();
    for (int off = 1; off < 256; off <<= 1) {
        int x = (t >= off) ? lds[t - off] : 0;
        __syncthreads();
        lds[t] += x;
        __syncthreads();
    }
    if (t < B) chunk_sums[t] = lds[t] - v;
}

// ---- scan stage 3 ----
__global__ void scan3_kernel(int* __restrict__ rp, const int* __restrict__ chunk_sums,
                             int* __restrict__ cursor, int N, int E) {
    int i = blockIdx.x * blockDim.x + threadIdx.x;
    if (i < N) {
        int val = rp[i] + chunk_sums[i >> 10];
        rp[i] = val;
        cursor[i] = val;
    }
    if (i == 0) rp[N] = E;
}

// ---- partitioned CSR fill ----
__global__ void fill_part_kernel(const int* __restrict__ src, const int* __restrict__ dst,
                                 int* __restrict__ cursor, int* __restrict__ col,
                                 int E, int loN_per, int N) {
    int p   = blockIdx.x & (NPART - 1);
    int sub = blockIdx.x >> 3;
    int nsub = gridDim.x >> 3;
    int lo = p * loN_per;
    int hi = lo + loN_per; if (hi > N) hi = N;
    for (int e = sub * blockDim.x + threadIdx.x; e < E; e += nsub * blockDim.x) {
        int d = dst[e];
        if (d >= lo && d < hi) {
            int pos = atomicAdd(&cursor[d], 1);
            col[pos] = src[e];
        }
    }
}

// ---- init: w0 half-rows; half h=(c>>2), chunk (c&3) ----
// state layout per hop k: base + k*N*64; half h at + h*N*32; node n at + n*32
__global__ void init_w0_half_kernel(const float* __restrict__ feats,
                                    const float* __restrict__ norm,
                                    __half* __restrict__ w, int N) {
    int wv   = threadIdx.x >> 6;
    int lane = threadIdx.x & 63;
    int n = blockIdx.x * 32 + wv * 8 + (lane >> 3);
    int c = lane & 7;
    if (n >= N) return;
    float nm = norm[n];
    const float4* f = (const float4*)(feats + (size_t)n * DIM + c * 8);
    float4 a = f[0], b = f[1];
    __half2 hv[4];
    hv[0] = __floats2half2_rn(a.x * nm, a.y * nm);
    hv[1] = __floats2half2_rn(a.z * nm, a.w * nm);
    hv[2] = __floats2half2_rn(b.x * nm, b.y * nm);
    hv[3] = __floats2half2_rn(b.z * nm, b.w * nm);
    size_t dstoff = (size_t)(c >> 2) * N * 32 + (size_t)n * 32 + (size_t)(c & 3) * 8;
    *(float4*)(w + dstoff) = *(const float4*)hv;
}

// ---- half hop: wave = 2 nodes x 8 edge slots x 4 chunks (16B) ----
// gathers 64B rows from a 6.4 MB half-plane; 4 contiguous lanes cover a row.
__global__ void gather_hop_half_kernel(const __half* __restrict__ wh,   // cur half base [N][32]
                                       const int* __restrict__ rp,
                                       const int* __restrict__ col,
                                       const float* __restrict__ norm,
                                       __half* __restrict__ wnexth,     // next half base
                                       int N) {
    int lane = threadIdx.x & 63;
    int nsub = lane >> 5;            // node sub 0..1  (bit 5)
    int e    = (lane >> 2) & 7;      // edge slot 0..7 (bits 2..4)
    int c    = lane & 3;             // 16B chunk 0..3 (bits 0..1)
    int n = blockIdx.x * ((blockDim.x >> 6) * 2) + ((threadIdx.x >> 6) * 2) + nsub;
    if (n >= N) return;              // folds are xor{4,8,16}: never cross bit 5

    int beg = rp[n];
    int end = rp[n + 1];
    float nm = norm[n];

    float acc[8];
    #pragma unroll
    for (int i = 0; i < 8; ++i) acc[i] = 0.0f;

    // trips 0,1 predicated (covers deg <= 16, ~84% of nodes)
    #pragma unroll
    for (int t = 0; t < 2; ++t) {
        int j = beg + e + (t << 3);
        if (j < end) {
            int cc = col[j];
            float4 raw = *(const float4*)(wh + (size_t)cc * 32 + (c << 3));
            const __half2* h2 = (const __half2*)&raw;
            float2 f0 = __half22float2(h2[0]);
            float2 f1 = __half22float2(h2[1]);
            float2 f2 = __half22float2(h2[2]);
            float2 f3 = __half22float2(h2[3]);
            acc[0] += f0.x; acc[1] += f0.y;
            acc[2] += f1.x; acc[3] += f1.y;
            acc[4] += f2.x; acc[5] += f2.y;
            acc[6] += f3.x; acc[7] += f3.y;
        }
    }
    // tail (deg > 16): per-lane loop, no shuffles inside
    for (int j = beg + 16 + e; j < end; j += 8) {
        int cc = col[j];
        float4 raw = *(const float4*)(wh + (size_t)cc * 32 + (c << 3));
        const __half2* h2 = (const __half2*)&raw;
        float2 f0 = __half22float2(h2[0]);
        float2 f1 = __half22float2(h2[1]);
        float2 f2 = __half22float2(h2[2]);
        float2 f3 = __half22float2(h2[3]);
        acc[0] += f0.x; acc[1] += f0.y;
        acc[2] += f1.x; acc[3] += f1.y;
        acc[4] += f2.x; acc[5] += f2.y;
        acc[6] += f3.x; acc[7] += f3.y;
    }

    // fold edge slots: xor 4,8,16 (bits 2..4); stays within the node's half-wave
    #pragma unroll
    for (int off = 4; off < 32; off <<= 1) {
        #pragma unroll
        for (int i = 0; i < 8; ++i) acc[i] += __shfl_xor(acc[i], off, 64);
    }

    if (e == 0) {   // lanes nsub*32 + c : 4 contiguous 16B writes = one 64B row
        float n2 = nm * nm;
        __half2 hv[4];
        hv[0] = __floats2half2_rn(acc[0] * n2, acc[1] * n2);
        hv[1] = __floats2half2_rn(acc[2] * n2, acc[3] * n2);
        hv[2] = __floats2half2_rn(acc[4] * n2, acc[5] * n2);
        hv[3] = __floats2half2_rn(acc[6] * n2, acc[7] * n2);
        *(float4*)(wnexth + (size_t)n * 32 + (c << 3)) = *(const float4*)hv;
    }
}

// ---- wide readout over half-row layout: lanes = (k-slot x chunk) ----
__global__ void readout_kernel(const __half* __restrict__ wbase,
                               const float* __restrict__ norm,
                               const float* __restrict__ s,
                               float* __restrict__ out,
                               int N, int nk, size_t kstride) {
    int n = blockIdx.x * (blockDim.x >> 6) + (threadIdx.x >> 6);
    if (n >= N) return;
    int lane  = threadIdx.x & 63;
    int e_sub = lane >> 3;   // k slot 0..7
    int c     = lane & 7;    // feature chunk

    float4 sa = *(const float4*)(s + (c << 3));
    float4 sb = *(const float4*)(s + (c << 3) + 4);

    float inm = 1.0f / norm[n];
    size_t choff = (size_t)(c >> 2) * N * 32 + (size_t)n * 32 + (size_t)(c & 3) * 8;

    float acc[8];
    #pragma unroll
    for (int i = 0; i < 8; ++i) acc[i] = 0.0f;

    #pragma unroll
    for (int iter = 0; iter < 2; ++iter) {
        int k = e_sub + iter * 8;
        float h[8];
        if (k < nk) {
            float4 raw = *(const float4*)(wbase + (size_t)k * kstride + choff);
            const __half2* h2 = (const __half2*)&raw;
            float2 f0 = __half22float2(h2[0]);
            float2 f1 = __half22float2(h2[1]);
            float2 f2 = __half22float2(h2[2]);
            float2 f3 = __half22float2(h2[3]);
            h[0] = f0.x * inm; h[1] = f0.y * inm;
            h[2] = f1.x * inm; h[3] = f1.y * inm;
            h[4] = f2.x * inm; h[5] = f2.y * inm;
            h[6] = f3.x * inm; h[7] = f3.y * inm;
        } else {
            #pragma unroll
            for (int i = 0; i < 8; ++i) h[i] = 0.0f;
        }
        float p = h[0] * sa.x + h[1] * sa.y + h[2] * sa.z + h[3] * sa.w
                + h[4] * sb.x + h[5] * sb.y + h[6] * sb.z + h[7] * sb.w;
        #pragma unroll
        for (int off = 1; off < 8; off <<= 1) p += __shfl_xor(p, off, 64);
        float gate = 1.0f / (1.0f + expf(-p));
        #pragma unroll
        for (int i = 0; i < 8; ++i) acc[i] += gate * h[i];
    }

    #pragma unroll
    for (int off = 8; off < 64; off <<= 1) {
        #pragma unroll
        for (int i = 0; i < 8; ++i) acc[i] += __shfl_xor(acc[i], off, 64);
    }

    if (e_sub == 0) {
        size_t rowbase = ((size_t)n << 6) + (c << 3);
        float4 o0 = make_float4(acc[0], acc[1], acc[2], acc[3]);
        float4 o1 = make_float4(acc[4], acc[5], acc[6], acc[7]);
        float4* o = (float4*)(out + rowbase);
        o[0] = o0; o[1] = o1;
    }
}

// ---- fallback (small ws): node-major fused path ----
__global__ void init_kernel(const float* __restrict__ feats,
                            const float* __restrict__ norm,
                            const float* __restrict__ s,
                            float* __restrict__ out,
                            __half* __restrict__ w, int N) {
    int n = blockIdx.x * (blockDim.x >> 6) + (threadIdx.x >> 6);
    int lane = threadIdx.x & 63;
    if (n >= N) return;
    size_t idx = ((size_t)n << 6) + lane;
    float v = feats[idx];
    float p = v * s[lane];
    #pragma unroll
    for (int off = 32; off; off >>= 1) p += __shfl_xor(p, off, 64);
    float gate = 1.0f / (1.0f + expf(-p));
    out[idx] = gate * v;
    w[idx] = __float2half(v * norm[n]);
}

__global__ void gather_hop_kernel(const __half* __restrict__ w,
                                  const int* __restrict__ rp,
                                  const int* __restrict__ col,
                                  const float* __restrict__ norm,
                                  const float* __restrict__ s,
                                  float* __restrict__ out,
                                  __half* __restrict__ wnext,
                                  int N, int write_next) {
    int n = blockIdx.x * (blockDim.x >> 6) + (threadIdx.x >> 6);
    if (n >= N) return;
    int lane = threadIdx.x & 63;
    int e_sub = lane >> 3;
    int c     = lane & 7;

    int beg = rp[n];
    int end = rp[n + 1];

    float acc[8];
    #pragma unroll
    for (int i = 0; i < 8; ++i) acc[i] = 0.0f;

    for (int j = beg + e_sub; j < end; j += 8) {
        int cc = col[j];
        float4 raw = *(const float4*)(w + ((size_t)cc << 6) + (c << 3));
        const __half2* h2 = (const __half2*)&raw;
        float2 f0 = __half22float2(h2[0]);
        float2 f1 = __half22float2(h2[1]);
        float2 f2 = __half22float2(h2[2]);
        float2 f3 = __half22float2(h2[3]);
        acc[0] += f0.x; acc[1] += f0.y;
        acc[2] += f1.x; acc[3] += f1.y;
        acc[4] += f2.x; acc[5] += f2.y;
        acc[6] += f3.x; acc[7] += f3.y;
    }

    #pragma unroll
    for (int off = 8; off < 64; off <<= 1) {
        #pragma unroll
        for (int i = 0; i < 8; ++i) acc[i] += __shfl_xor(acc[i], off, 64);
    }

    float nm = norm[n];
    float v[8];
    #pragma unroll
    for (int i = 0; i < 8; ++i) v[i] = acc[i] * nm;

    float4 sa = *(const float4*)(s + (c << 3));
    float4 sb = *(const float4*)(s + (c << 3) + 4);
    float p = v[0] * sa.x + v[1] * sa.y + v[2] * sa.z + v[3] * sa.w
            + v[4] * sb.x + v[5] * sb.y + v[6] * sb.z + v[7] * sb.w;
    #pragma unroll
    for (int off = 1; off < 8; off <<= 1) p += __shfl_xor(p, off, 64);
    float gate = 1.0f / (1.0f + expf(-p));

    size_t base = ((size_t)n << 6) + (c << 3);
    if (e_sub == 0) {
        float4* o = (float4*)(out + base);
        float4 o0 = o[0], o1 = o[1];
        o0.x += gate * v[0]; o0.y += gate * v[1];
        o0.z += gate * v[2]; o0.w += gate * v[3];
        o1.x += gate * v[4]; o1.y += gate * v[5];
        o1.z += gate * v[6]; o1.w += gate * v[7];
        o[0] = o0; o[1] = o1;
    } else if (e_sub == 1 && write_next) {
        __half2 hv[4];
        hv[0] = __floats2half2_rn(v[0] * nm, v[1] * nm);
        hv[1] = __floats2half2_rn(v[2] * nm, v[3] * nm);
        hv[2] = __floats2half2_rn(v[4] * nm, v[5] * nm);
        hv[3] = __floats2half2_rn(v[6] * nm, v[7] * nm);
        *(float4*)(wnext + base) = *(const float4*)hv;
    }
}

extern "C" void kernel_launch(void* const* d_in, const int* in_sizes, int n_in,
                              void* d_out, int out_size, void* d_ws, size_t ws_size,
                              hipStream_t stream) {
    const float* feats = (const float*)d_in[0];
    const float* s     = (const float*)d_in[1];
    const int*   src   = (const int*)d_in[2];
    const int*   dst   = (const int*)d_in[3];
    float* out = (float*)d_out;

    const int N = in_sizes[0] / DIM;
    const int E = in_sizes[2];
    const int K = 10;

    const int BLK = 256;
    const int wavesPerBlk = BLK / 64;
    const int chunks = (N + 1023) / 1024;   // must be <= 256
    int nodeBlocks = (N + wavesPerBlk - 1) / wavesPerBlk;
    int halfHopBlocks = (N + 7) / 8;        // 8 nodes/block (4 waves x 2 nodes)
    int initBlocks = (N + 31) / 32;         // 32 nodes/block
    int intCount = (N + 1) + N + N + E + 256;
    int nodesPerPart = (N + NPART - 1) / NPART;
    const int PART_BLOCKS = 2048;

    size_t stateElems = (size_t)N * DIM;    // per hop (2 halves of N*32)
    size_t need_full = (size_t)N * 4 + (size_t)(K + 1) * stateElems * 2
                     + (size_t)intCount * 4 + 64;
    int full = (ws_size >= need_full) ? 1 : 0;
    int nbuf = full ? (K + 1) : 2;

    float*  norm  = (float*)d_ws;
    __half* wbase = (__half*)(norm + N);
    int*    rp     = (int*)(wbase + (size_t)nbuf * stateElems);
    int*    deg    = rp + (N + 1);
    int*    cursor = deg + N;
    int*    col    = cursor + N;
    int*    chunk  = col + E;

    zero_int_kernel<<<(N + BLK - 1) / BLK, BLK, 0, stream>>>(deg, N);
    degree_part_kernel<<<PART_BLOCKS, BLK, 0, stream>>>(dst, deg, E, nodesPerPart, N);
    norm_kernel<<<(N + BLK - 1) / BLK, BLK, 0, stream>>>(deg, norm, N);

    scan1_kernel<<<chunks, 256, 0, stream>>>(deg, rp, chunk, N);
    scan2_kernel<<<1, 256, 0, stream>>>(chunk, chunks);
    scan3_kernel<<<(N + BLK - 1) / BLK, BLK, 0, stream>>>(rp, chunk, cursor, N, E);
    fill_part_kernel<<<PART_BLOCKS, BLK, 0, stream>>>(src, dst, cursor, col,
                                                      E, nodesPerPart, N);

    if (full) {
        init_w0_half_kernel<<<initBlocks, BLK, 0, stream>>>(feats, norm, wbase, N);
        size_t halfElems = (size_t)N * 32;
        for (int k = 0; k < K; ++k) {
            const __half* cur = wbase + (size_t)k * stateElems;
            __half* nxt = wbase + (size_t)(k + 1) * stateElems;
            for (int h = 0; h < 2; ++h) {
                gather_hop_half_kernel<<<halfHopBlocks, BLK, 0, stream>>>(
                    cur + (size_t)h * halfElems, rp, col, norm,
                    nxt + (size_t)h * halfElems, N);
            }
        }
        readout_kernel<<<nodeBlocks, BLK, 0, stream>>>(wbase, norm, s, out,
                                                       N, K + 1, stateElems);
    } else {
        __half* wA = wbase;
        __half* wB = wbase + stateElems;
        init_kernel<<<nodeBlocks, BLK, 0, stream>>>(feats, norm, s, out, wA, N);
        __half* cur = wA;
        __half* nxt = wB;
        for (int k = 0; k < K; ++k) {
            int write_next = (k < K - 1) ? 1 : 0;
            gather_hop_kernel<<<nodeBlocks, BLK, 0, stream>>>(cur, rp, col, norm, s,
                                                              out, nxt, N, write_next);
            __half* t = cur; cur = nxt; nxt = t;
        }
    }
}

// Round 13
// 535.929 us; speedup vs baseline: 1.3673x; 1.2772x over previous
//
#include <hip/hip_runtime.h>
#include <hip/hip_bf16.h>
#include <hip/hip_fp16.h>
#include <math.h>

// DAGNN propagation, CSR-gather, fp16 state, wide gather (8 edges/wave-instr).
// Round 13: compute path = round-10 (best, 580us). Build rewritten as an
// LDS-binned two-phase CSR construction:
//   A1: bucket histogram (bucket = 512 nodes) via LDS bins
//   S : 196-bucket exclusive scan (1 block); also rp[N]=E, tail init
//   A2: per-block LDS binning of a 4096-edge chunk + ONE global atomic per
//       (bucket,block) range reservation -> coalesced pair writes (~1x amp)
//   B : one block per bucket: LDS degree count -> LDS scan -> rp/norm/col
// Replaces degree_part + norm + scan1/2/3 + fill_part (~100us -> ~40us).

#define DIM 64
#define BSH 9
#define BSZ 512                 // nodes per bucket
#define MAXNB 256               // buckets must fit one 256-thread scan block
#define A2_CHUNK 4096           // edges per A2 block

// ---- zero int region ----
__global__ void zero_int_kernel(int* __restrict__ p, int n) {
    int i = blockIdx.x * blockDim.x + threadIdx.x;
    if (i < n) p[i] = 0;
}

// ---- A1: bucket histogram via LDS bins ----
__global__ void bin_count_kernel(const int* __restrict__ dst,
                                 int* __restrict__ binCount, int E) {
    __shared__ int lb[MAXNB];
    if (threadIdx.x < MAXNB) lb[threadIdx.x] = 0;
    __syncthreads();
    for (int e = blockIdx.x * blockDim.x + threadIdx.x; e < E;
         e += gridDim.x * blockDim.x) {
        atomicAdd(&lb[dst[e] >> BSH], 1);
    }
    __syncthreads();
    if (threadIdx.x < MAXNB && lb[threadIdx.x])
        atomicAdd(&binCount[threadIdx.x], lb[threadIdx.x]);
}

// ---- S: exclusive scan of bucket counts; init tails; rp[N]=E ----
__global__ void binscan_kernel(const int* __restrict__ binCount,
                               int* __restrict__ binBase, int* __restrict__ tail,
                               int* __restrict__ rp, int NB, int N, int E) {
    __shared__ int lds[256];
    int t = threadIdx.x;
    int v = (t < NB) ? binCount[t] : 0;
    lds[t] = v;
    __syncthreads();
    for (int off = 1; off < 256; off <<= 1) {
        int x = (t >= off) ? lds[t - off] : 0;
        __syncthreads();
        lds[t] += x;
        __syncthreads();
    }
    int excl = lds[t] - v;
    if (t < NB) { binBase[t] = excl; tail[t] = excl; }
    if (t == 0) { binBase[NB] = E; rp[N] = E; }
}

// ---- A2: LDS-binned scatter of (src,dst) pairs into bucket regions ----
__global__ void bin_scatter_kernel(const int* __restrict__ src,
                                   const int* __restrict__ dst,
                                   int* __restrict__ tail,
                                   int2* __restrict__ pairs, int E) {
    __shared__ int cnt[MAXNB];
    __shared__ int base[MAXNB];
    int t = threadIdx.x;
    int begE = blockIdx.x * A2_CHUNK;
    int endE = begE + A2_CHUNK; if (endE > E) endE = E;
    if (t < MAXNB) cnt[t] = 0;
    __syncthreads();
    for (int e = begE + t; e < endE; e += blockDim.x)
        atomicAdd(&cnt[dst[e] >> BSH], 1);
    __syncthreads();
    if (t < MAXNB) {
        int c = cnt[t];
        base[t] = c ? atomicAdd(&tail[t], c) : 0;   // one global atomic / bucket / block
        cnt[t] = 0;                                  // reuse as local cursor
    }
    __syncthreads();
    for (int e = begE + t; e < endE; e += blockDim.x) {
        int d = dst[e];
        int b = d >> BSH;
        int pos = base[b] + atomicAdd(&cnt[b], 1);
        pairs[pos] = make_int2(src[e], d);           // coalesced-ish: ~168B windows
    }
}

// ---- B: per-bucket CSR finalize: degree -> scan -> rp/norm/col ----
__global__ void bucket_build_kernel(const int2* __restrict__ pairs,
                                    const int* __restrict__ binBase,
                                    int* __restrict__ col, int* __restrict__ rp,
                                    float* __restrict__ norm, int N) {
    __shared__ int degL[BSZ];
    __shared__ int off[BSZ];
    __shared__ int tmp[256];
    int b  = blockIdx.x;
    int lo = b << BSH;
    int cnt = N - lo; if (cnt > BSZ) cnt = BSZ;
    int t = threadIdx.x;
    degL[t] = 0; degL[t + 256] = 0;
    __syncthreads();
    int rbeg = binBase[b], rend = binBase[b + 1];
    for (int j = rbeg + t; j < rend; j += 256)
        atomicAdd(&degL[pairs[j].y - lo], 1);
    __syncthreads();
    int d0 = degL[2 * t], d1 = degL[2 * t + 1];
    int s2 = d0 + d1;
    tmp[t] = s2;
    __syncthreads();
    for (int o = 1; o < 256; o <<= 1) {
        int x = (t >= o) ? tmp[t - o] : 0;
        __syncthreads();
        tmp[t] += x;
        __syncthreads();
    }
    int e2 = tmp[t] - s2;                  // local exclusive offset
    off[2 * t]     = e2;
    off[2 * t + 1] = e2 + d0;
    __syncthreads();
    if (2 * t < cnt) {
        rp[lo + 2 * t] = rbeg + e2;
        norm[lo + 2 * t] = rsqrtf((float)d0);
    }
    if (2 * t + 1 < cnt) {
        rp[lo + 2 * t + 1] = rbeg + e2 + d0;
        norm[lo + 2 * t + 1] = rsqrtf((float)d1);
    }
    for (int j = rbeg + t; j < rend; j += 256) {
        int2 p = pairs[j];
        int slot = atomicAdd(&off[p.y - lo], 1);     // local cursor
        col[rbeg + slot] = p.x;                      // L2-hot 27KB window
    }
}

// ---- init (full path): w0 = half(feats*norm), node-major 128B rows ----
__global__ void init_w0_kernel(const float* __restrict__ feats,
                               const float* __restrict__ norm,
                               __half* __restrict__ w, int N) {
    int n = blockIdx.x * (blockDim.x >> 6) + (threadIdx.x >> 6);
    int lane = threadIdx.x & 63;
    if (n >= N) return;
    size_t idx = ((size_t)n << 6) + lane;
    w[idx] = __float2half(feats[idx] * norm[n]);
}

// ---- hop (round-10): wide gather w/ col-preload, uniform-trip shuffle ----
__global__ void gather_hop_store_kernel(const __half* __restrict__ w,
                                        const int* __restrict__ rp,
                                        const int* __restrict__ col,
                                        const float* __restrict__ norm,
                                        __half* __restrict__ wnext, int N) {
    int n = blockIdx.x * (blockDim.x >> 6) + (threadIdx.x >> 6);
    if (n >= N) return;
    int lane  = threadIdx.x & 63;
    int e_sub = lane >> 3;
    int c     = lane & 7;

    int beg = rp[n];
    int end = rp[n + 1];
    int deg = end - beg;
    float nm = norm[n];

    int myc = 0;
    if (lane < deg) myc = col[beg + lane];

    float acc[8];
    #pragma unroll
    for (int i = 0; i < 8; ++i) acc[i] = 0.0f;

    int nfull = (deg < 64) ? deg : 64;

    {   // trips 0,1 unconditional loads, masked accumulate (deg<=16: ~84%)
        int cc0 = __shfl(myc, e_sub, 64);
        int cc1 = __shfl(myc, e_sub + 8, 64);
        float4 raw0 = *(const float4*)(w + ((size_t)cc0 << 6) + (c << 3));
        float4 raw1 = *(const float4*)(w + ((size_t)cc1 << 6) + (c << 3));
        if (e_sub < nfull) {
            const __half2* h2 = (const __half2*)&raw0;
            float2 f0 = __half22float2(h2[0]);
            float2 f1 = __half22float2(h2[1]);
            float2 f2 = __half22float2(h2[2]);
            float2 f3 = __half22float2(h2[3]);
            acc[0] += f0.x; acc[1] += f0.y;
            acc[2] += f1.x; acc[3] += f1.y;
            acc[4] += f2.x; acc[5] += f2.y;
            acc[6] += f3.x; acc[7] += f3.y;
        }
        if (e_sub + 8 < nfull) {
            const __half2* h2 = (const __half2*)&raw1;
            float2 f0 = __half22float2(h2[0]);
            float2 f1 = __half22float2(h2[1]);
            float2 f2 = __half22float2(h2[2]);
            float2 f3 = __half22float2(h2[3]);
            acc[0] += f0.x; acc[1] += f0.y;
            acc[2] += f1.x; acc[3] += f1.y;
            acc[4] += f2.x; acc[5] += f2.y;
            acc[6] += f3.x; acc[7] += f3.y;
        }
    }
    int ntrips = (nfull + 7) >> 3;
    for (int t = 2; t < ntrips; ++t) {
        int jj = e_sub + (t << 3);
        int cc = __shfl(myc, jj, 64);
        float4 raw = *(const float4*)(w + ((size_t)cc << 6) + (c << 3));
        if (jj < nfull) {
            const __half2* h2 = (const __half2*)&raw;
            float2 f0 = __half22float2(h2[0]);
            float2 f1 = __half22float2(h2[1]);
            float2 f2 = __half22float2(h2[2]);
            float2 f3 = __half22float2(h2[3]);
            acc[0] += f0.x; acc[1] += f0.y;
            acc[2] += f1.x; acc[3] += f1.y;
            acc[4] += f2.x; acc[5] += f2.y;
            acc[6] += f3.x; acc[7] += f3.y;
        }
    }
    for (int j = beg + 64 + e_sub; j < end; j += 8) {   // deg>64 tail (rare)
        int cc = col[j];
        float4 raw = *(const float4*)(w + ((size_t)cc << 6) + (c << 3));
        const __half2* h2 = (const __half2*)&raw;
        float2 f0 = __half22float2(h2[0]);
        float2 f1 = __half22float2(h2[1]);
        float2 f2 = __half22float2(h2[2]);
        float2 f3 = __half22float2(h2[3]);
        acc[0] += f0.x; acc[1] += f0.y;
        acc[2] += f1.x; acc[3] += f1.y;
        acc[4] += f2.x; acc[5] += f2.y;
        acc[6] += f3.x; acc[7] += f3.y;
    }

    #pragma unroll
    for (int off = 8; off < 64; off <<= 1) {
        #pragma unroll
        for (int i = 0; i < 8; ++i) acc[i] += __shfl_xor(acc[i], off, 64);
    }

    if (e_sub == 0) {
        float n2 = nm * nm;
        __half2 hv[4];
        hv[0] = __floats2half2_rn(acc[0] * n2, acc[1] * n2);
        hv[1] = __floats2half2_rn(acc[2] * n2, acc[3] * n2);
        hv[2] = __floats2half2_rn(acc[4] * n2, acc[5] * n2);
        hv[3] = __floats2half2_rn(acc[6] * n2, acc[7] * n2);
        *(float4*)(wnext + ((size_t)n << 6) + (c << 3)) = *(const float4*)hv;
    }
}

// ---- wide readout (round-10): lanes = (k-slot x chunk), 16B loads ----
__global__ void readout_kernel(const __half* __restrict__ wbase,
                               const float* __restrict__ norm,
                               const float* __restrict__ s,
                               float* __restrict__ out,
                               int N, int nk, size_t kstride) {
    int n = blockIdx.x * (blockDim.x >> 6) + (threadIdx.x >> 6);
    if (n >= N) return;
    int lane  = threadIdx.x & 63;
    int e_sub = lane >> 3;
    int c     = lane & 7;

    float4 sa = *(const float4*)(s + (c << 3));
    float4 sb = *(const float4*)(s + (c << 3) + 4);

    float inm = 1.0f / norm[n];
    size_t rowbase = ((size_t)n << 6) + (c << 3);

    float acc[8];
    #pragma unroll
    for (int i = 0; i < 8; ++i) acc[i] = 0.0f;

    #pragma unroll
    for (int iter = 0; iter < 2; ++iter) {
        int k = e_sub + iter * 8;
        float h[8];
        if (k < nk) {
            float4 raw = *(const float4*)(wbase + rowbase + (size_t)k * kstride);
            const __half2* h2 = (const __half2*)&raw;
            float2 f0 = __half22float2(h2[0]);
            float2 f1 = __half22float2(h2[1]);
            float2 f2 = __half22float2(h2[2]);
            float2 f3 = __half22float2(h2[3]);
            h[0] = f0.x * inm; h[1] = f0.y * inm;
            h[2] = f1.x * inm; h[3] = f1.y * inm;
            h[4] = f2.x * inm; h[5] = f2.y * inm;
            h[6] = f3.x * inm; h[7] = f3.y * inm;
        } else {
            #pragma unroll
            for (int i = 0; i < 8; ++i) h[i] = 0.0f;
        }
        float p = h[0] * sa.x + h[1] * sa.y + h[2] * sa.z + h[3] * sa.w
                + h[4] * sb.x + h[5] * sb.y + h[6] * sb.z + h[7] * sb.w;
        #pragma unroll
        for (int off = 1; off < 8; off <<= 1) p += __shfl_xor(p, off, 64);
        float gate = 1.0f / (1.0f + expf(-p));
        #pragma unroll
        for (int i = 0; i < 8; ++i) acc[i] += gate * h[i];
    }

    #pragma unroll
    for (int off = 8; off < 64; off <<= 1) {
        #pragma unroll
        for (int i = 0; i < 8; ++i) acc[i] += __shfl_xor(acc[i], off, 64);
    }

    if (e_sub == 0) {
        float4 o0 = make_float4(acc[0], acc[1], acc[2], acc[3]);
        float4 o1 = make_float4(acc[4], acc[5], acc[6], acc[7]);
        float4* o = (float4*)(out + rowbase);
        o[0] = o0; o[1] = o1;
    }
}

// ---- fallback (small ws): fused hop with out RMW ----
__global__ void init_kernel(const float* __restrict__ feats,
                            const float* __restrict__ norm,
                            const float* __restrict__ s,
                            float* __restrict__ out,
                            __half* __restrict__ w, int N) {
    int n = blockIdx.x * (blockDim.x >> 6) + (threadIdx.x >> 6);
    int lane = threadIdx.x & 63;
    if (n >= N) return;
    size_t idx = ((size_t)n << 6) + lane;
    float v = feats[idx];
    float p = v * s[lane];
    #pragma unroll
    for (int off = 32; off; off >>= 1) p += __shfl_xor(p, off, 64);
    float gate = 1.0f / (1.0f + expf(-p));
    out[idx] = gate * v;
    w[idx] = __float2half(v * norm[n]);
}

__global__ void gather_hop_kernel(const __half* __restrict__ w,
                                  const int* __restrict__ rp,
                                  const int* __restrict__ col,
                                  const float* __restrict__ norm,
                                  const float* __restrict__ s,
                                  float* __restrict__ out,
                                  __half* __restrict__ wnext,
                                  int N, int write_next) {
    int n = blockIdx.x * (blockDim.x >> 6) + (threadIdx.x >> 6);
    if (n >= N) return;
    int lane = threadIdx.x & 63;
    int e_sub = lane >> 3;
    int c     = lane & 7;

    int beg = rp[n];
    int end = rp[n + 1];

    float acc[8];
    #pragma unroll
    for (int i = 0; i < 8; ++i) acc[i] = 0.0f;

    for (int j = beg + e_sub; j < end; j += 8) {
        int cc = col[j];
        float4 raw = *(const float4*)(w + ((size_t)cc << 6) + (c << 3));
        const __half2* h2 = (const __half2*)&raw;
        float2 f0 = __half22float2(h2[0]);
        float2 f1 = __half22float2(h2[1]);
        float2 f2 = __half22float2(h2[2]);
        float2 f3 = __half22float2(h2[3]);
        acc[0] += f0.x; acc[1] += f0.y;
        acc[2] += f1.x; acc[3] += f1.y;
        acc[4] += f2.x; acc[5] += f2.y;
        acc[6] += f3.x; acc[7] += f3.y;
    }

    #pragma unroll
    for (int off = 8; off < 64; off <<= 1) {
        #pragma unroll
        for (int i = 0; i < 8; ++i) acc[i] += __shfl_xor(acc[i], off, 64);
    }

    float nm = norm[n];
    float v[8];
    #pragma unroll
    for (int i = 0; i < 8; ++i) v[i] = acc[i] * nm;

    float4 sa = *(const float4*)(s + (c << 3));
    float4 sb = *(const float4*)(s + (c << 3) + 4);
    float p = v[0] * sa.x + v[1] * sa.y + v[2] * sa.z + v[3] * sa.w
            + v[4] * sb.x + v[5] * sb.y + v[6] * sb.z + v[7] * sb.w;
    #pragma unroll
    for (int off = 1; off < 8; off <<= 1) p += __shfl_xor(p, off, 64);
    float gate = 1.0f / (1.0f + expf(-p));

    size_t base = ((size_t)n << 6) + (c << 3);
    if (e_sub == 0) {
        float4* o = (float4*)(out + base);
        float4 o0 = o[0], o1 = o[1];
        o0.x += gate * v[0]; o0.y += gate * v[1];
        o0.z += gate * v[2]; o0.w += gate * v[3];
        o1.x += gate * v[4]; o1.y += gate * v[5];
        o1.z += gate * v[6]; o1.w += gate * v[7];
        o[0] = o0; o[1] = o1;
    } else if (e_sub == 1 && write_next) {
        __half2 hv[4];
        hv[0] = __floats2half2_rn(v[0] * nm, v[1] * nm);
        hv[1] = __floats2half2_rn(v[2] * nm, v[3] * nm);
        hv[2] = __floats2half2_rn(v[4] * nm, v[5] * nm);
        hv[3] = __floats2half2_rn(v[6] * nm, v[7] * nm);
        *(float4*)(wnext + base) = *(const float4*)hv;
    }
}

extern "C" void kernel_launch(void* const* d_in, const int* in_sizes, int n_in,
                              void* d_out, int out_size, void* d_ws, size_t ws_size,
                              hipStream_t stream) {
    const float* feats = (const float*)d_in[0];
    const float* s     = (const float*)d_in[1];
    const int*   src   = (const int*)d_in[2];
    const int*   dst   = (const int*)d_in[3];
    float* out = (float*)d_out;

    const int N = in_sizes[0] / DIM;
    const int E = in_sizes[2];
    const int K = 10;
    const int NB = (N + BSZ - 1) >> BSH;    // 196 for N=100000; must be <= 256

    const int BLK = 256;
    const int wavesPerBlk = BLK / 64;
    int nodeBlocks = (N + wavesPerBlk - 1) / wavesPerBlk;
    int a2Blocks = (E + A2_CHUNK - 1) / A2_CHUNK;

    size_t stateElems = (size_t)N * DIM;
    // ws layout: norm(N f) | wbase(nbuf*stateElems h) | rp(N+1) | col(E)
    //            | binCount(256) | binBase(257) | tail(256) | pad | pairs(E int2)
    size_t intCount = (size_t)(N + 1) + E + 256 + 257 + 256;
    size_t need_full = (size_t)N * 4 + (size_t)(K + 1) * stateElems * 2
                     + intCount * 4 + (size_t)E * 8 + 64;
    int full = (ws_size >= need_full) ? 1 : 0;
    int nbuf = full ? (K + 1) : 2;

    float*  norm    = (float*)d_ws;
    __half* wbase   = (__half*)(norm + N);
    int*    rp      = (int*)(wbase + (size_t)nbuf * stateElems);
    int*    col     = rp + (N + 1);
    int*    binCount= col + E;
    int*    binBase = binCount + 256;
    int*    tail    = binBase + 257;
    size_t  poff    = (size_t)((char*)(tail + 256) - (char*)d_ws);
    poff = (poff + 7) & ~(size_t)7;
    int2*   pairs   = (int2*)((char*)d_ws + poff);

    // ---- build: histogram -> scan -> binned scatter -> bucket finalize ----
    zero_int_kernel<<<1, 256, 0, stream>>>(binCount, 256);
    bin_count_kernel<<<512, BLK, 0, stream>>>(dst, binCount, E);
    binscan_kernel<<<1, 256, 0, stream>>>(binCount, binBase, tail, rp, NB, N, E);
    bin_scatter_kernel<<<a2Blocks, BLK, 0, stream>>>(src, dst, tail, pairs, E);
    bucket_build_kernel<<<NB, 256, 0, stream>>>(pairs, binBase, col, rp, norm, N);

    if (full) {
        init_w0_kernel<<<nodeBlocks, BLK, 0, stream>>>(feats, norm, wbase, N);
        for (int k = 0; k < K; ++k) {
            const __half* cur = wbase + (size_t)k * stateElems;
            __half* nxt = wbase + (size_t)(k + 1) * stateElems;
            gather_hop_store_kernel<<<nodeBlocks, BLK, 0, stream>>>(cur, rp, col,
                                                                    norm, nxt, N);
        }
        readout_kernel<<<nodeBlocks, BLK, 0, stream>>>(wbase, norm, s, out,
                                                       N, K + 1, stateElems);
    } else {
        __half* wA = wbase;
        __half* wB = wbase + stateElems;
        init_kernel<<<nodeBlocks, BLK, 0, stream>>>(feats, norm, s, out, wA, N);
        __half* cur = wA;
        __half* nxt = wB;
        for (int k = 0; k < K; ++k) {
            int write_next = (k < K - 1) ? 1 : 0;
            gather_hop_kernel<<<nodeBlocks, BLK, 0, stream>>>(cur, rp, col, norm, s,
                                                              out, nxt, N, write_next);
            __half* t = cur; cur = nxt; nxt = t;
        }
    }
}